// Round 1
// baseline (494.707 us; speedup 1.0000x reference)
//
#include <hip/hip_runtime.h>

// Problem constants
#define NROWS 8192   // rows of x / out
#define IN_F  4096   // K
#define OUT_F 4096   // output features
#define NPART 2048   // partial slots (= stats grid size)

typedef __attribute__((ext_vector_type(4))) int i32x4;

// ---------------------------------------------------------------------------
// Static device scratch. Fully rewritten on every kernel_launch call.
// ---------------------------------------------------------------------------
__device__ double g_wsum_p[NPART];                  // per-block sum|w| (fp64)
__device__ float  g_sx[NROWS];                      // per-row x scale = rowmax/127
__device__ signed char g_wq[(size_t)OUT_F * IN_F];  // 16 MiB ternary i8
__device__ signed char g_xq[(size_t)NROWS * IN_F];  // 32 MiB x in i8

// ---------------------------------------------------------------------------
// Kernel 1: w stats pass — sum|w| (fp64), per-block partials. No atomics.
// ---------------------------------------------------------------------------
__global__ __launch_bounds__(256) void tl_wstats(const float* __restrict__ w) {
    const int idx = blockIdx.x * blockDim.x + threadIdx.x;
    const int stride = gridDim.x * blockDim.x;

    double lsum = 0.0;
    const float4* w4 = (const float4*)w;
    for (int i = idx; i < OUT_F * IN_F / 4; i += stride) {
        float4 v = w4[i];
        lsum += (double)fabsf(v.x) + (double)fabsf(v.y) +
                (double)fabsf(v.z) + (double)fabsf(v.w);
    }
    for (int off = 32; off > 0; off >>= 1) lsum += __shfl_down(lsum, off, 64);
    __shared__ double ssum[4];
    int lane = threadIdx.x & 63, wv = threadIdx.x >> 6;
    if (lane == 0) ssum[wv] = lsum;
    __syncthreads();
    if (threadIdx.x == 0)
        g_wsum_p[blockIdx.x] = ssum[0] + ssum[1] + ssum[2] + ssum[3];
}

// ---------------------------------------------------------------------------
// Kernel 2: finalize w stats (per-block recompute from L2-resident partials),
// then quantize w -> ternary i8 (16 elements / thread / iter, 16 B stores).
// ---------------------------------------------------------------------------
__global__ __launch_bounds__(256) void tl_wquant(const float* __restrict__ w) {
    double s = 0.0;
    for (int i = threadIdx.x; i < NPART; i += 256) s += g_wsum_p[i];
    for (int off = 32; off > 0; off >>= 1) s += __shfl_down(s, off, 64);
    __shared__ double ssum[4];
    __shared__ float sh_thresh;
    int lane = threadIdx.x & 63, wv = threadIdx.x >> 6;
    if (lane == 0) ssum[wv] = s;
    __syncthreads();
    if (threadIdx.x == 0) {
        double tot = ssum[0] + ssum[1] + ssum[2] + ssum[3];
        sh_thresh = (float)(0.5 * tot / (double)((size_t)OUT_F * IN_F));
    }
    __syncthreads();
    const float thresh = sh_thresh;

    const int idx = blockIdx.x * blockDim.x + threadIdx.x;
    const int stride = gridDim.x * blockDim.x;

    const float4* w4 = (const float4*)w;
    i32x4* wout = (i32x4*)g_wq;
    for (int i = idx; i < OUT_F * IN_F / 16; i += stride) {
        signed char q[16];
#pragma unroll
        for (int j = 0; j < 4; ++j) {
            float4 v = w4[i * 4 + j];
            q[4*j+0] = v.x > thresh ? 1 : (v.x < -thresh ? -1 : 0);
            q[4*j+1] = v.y > thresh ? 1 : (v.y < -thresh ? -1 : 0);
            q[4*j+2] = v.z > thresh ? 1 : (v.z < -thresh ? -1 : 0);
            q[4*j+3] = v.w > thresh ? 1 : (v.w < -thresh ? -1 : 0);
        }
        i32x4 val; __builtin_memcpy(&val, q, 16);
        wout[i] = val;
    }
}

// ---------------------------------------------------------------------------
// Kernel 3: x per-row quantization, SINGLE PASS.
// One block per row; the row (4096 floats) is held in registers across the
// block (16 floats/thread), so x is read exactly once from HBM.
// scale_m = rowmax/127 factors out of the integer dot product exactly.
// ---------------------------------------------------------------------------
__global__ __launch_bounds__(256) void tl_xquant(const float* __restrict__ x) {
    const int row = blockIdx.x;
    const int tid = threadIdx.x;
    const float4* x4 = (const float4*)(x + (size_t)row * IN_F);

    float4 v[4];
    float lmax = 0.f;
#pragma unroll
    for (int j = 0; j < 4; ++j) {
        v[j] = x4[tid + j * 256];
        lmax = fmaxf(lmax, fmaxf(fmaxf(fabsf(v[j].x), fabsf(v[j].y)),
                                 fmaxf(fabsf(v[j].z), fabsf(v[j].w))));
    }
    for (int off = 32; off > 0; off >>= 1)
        lmax = fmaxf(lmax, __shfl_down(lmax, off, 64));
    __shared__ float smax[4];
    __shared__ float sh_inv;
    int lane = tid & 63, wv = tid >> 6;
    if (lane == 0) smax[wv] = lmax;
    __syncthreads();
    if (tid == 0) {
        float m = fmaxf(fmaxf(smax[0], smax[1]), fmaxf(smax[2], smax[3]));
        g_sx[row] = m * (1.f / 127.f);
        sh_inv = m > 0.f ? 127.f / m : 0.f;
    }
    __syncthreads();
    const float inv = sh_inv;

    int* xout = (int*)(g_xq + (size_t)row * IN_F);
#pragma unroll
    for (int j = 0; j < 4; ++j) {
        signed char q[4];
        q[0] = (signed char)(int)rintf(fminf(fmaxf(v[j].x * inv, -127.f), 127.f));
        q[1] = (signed char)(int)rintf(fminf(fmaxf(v[j].y * inv, -127.f), 127.f));
        q[2] = (signed char)(int)rintf(fminf(fmaxf(v[j].z * inv, -127.f), 127.f));
        q[3] = (signed char)(int)rintf(fminf(fmaxf(v[j].w * inv, -127.f), 127.f));
        int val; __builtin_memcpy(&val, q, 4);
        xout[tid + j * 256] = val;
    }
}

// ---------------------------------------------------------------------------
// Kernel 4: i8 GEMM  C[m,n] = (s_m * sum_k xq[m,k]*wq[n,k] + bias[n]) * gamma
// A = g_xq [M,K] i8, B = g_wq [N,K] i8 (both K-major).
// 128x128 block tile, BK=64, 256 threads (4 waves, 2x2 of 64x64),
// global_load_lds width-16 staging, ds_read_b128 fragments,
// mfma_i32_16x16x64_i8 4x4 per wave. 64 K-iters. (Unchanged except the
// per-row scale epilogue.)
// ---------------------------------------------------------------------------
#define GLD_LDS(gp, lp) \
    __builtin_amdgcn_global_load_lds( \
        (const __attribute__((address_space(1))) void*)(gp), \
        (__attribute__((address_space(3))) void*)(lp), 16, 0, 0)

__global__ __launch_bounds__(256) void tl_gemm_i8(
    const float* __restrict__ bias,
    const float* __restrict__ gamma_p,
    float* __restrict__ C) {
    constexpr int K = IN_F, N = OUT_F;
    constexpr int BK = 64;

    const signed char* __restrict__ A = g_xq;
    const signed char* __restrict__ B = g_wq;

    // LDS: element (row,k) at row*BK + k. Chunk c (16 B) at byte c*16 —
    // matches wave-uniform base + lane*16 scatter. NO padding, NO swizzle.
    __shared__ __align__(16) signed char As[128 * BK];
    __shared__ __align__(16) signed char Bs[128 * BK];

    const int tid  = threadIdx.x;
    const int lane = tid & 63;
    const int wave = tid >> 6;
    const int wm = (wave >> 1) * 64;
    const int wn = (wave & 1) * 64;

    const int rowBase = blockIdx.y * 128;   // M
    const int colBase = blockIdx.x * 128;   // N

    i32x4 acc[4][4] = {};

    // Staging: thread tid owns chunks tid and 256+tid.
    // chunk c -> row c>>2, byte offset (c&3)*16 within the 64 B row.
    const int r0  = tid >> 2;
    const int cc0 = (tid & 3) * 16;

    const signed char* A0 = A + (size_t)(rowBase + r0) * K + cc0;
    const signed char* A1 = A0 + (size_t)64 * K;
    const signed char* B0 = B + (size_t)(colBase + r0) * K + cc0;
    const signed char* B1 = B0 + (size_t)64 * K;

    char* lA = (char*)As;
    char* lB = (char*)Bs;
    const int lo0 = (wave * 64) * 16;
    const int lo1 = (256 + wave * 64) * 16;

    const int kq  = (lane >> 4) * 16;  // k byte offset of this lane's fragment
    const int r16 = lane & 15;         // row-in-16

    for (int kt = 0; kt < K; kt += BK) {
        GLD_LDS(A0 + kt, lA + lo0);
        GLD_LDS(A1 + kt, lA + lo1);
        GLD_LDS(B0 + kt, lB + lo0);
        GLD_LDS(B1 + kt, lB + lo1);
        __syncthreads();   // drains vmcnt -> LDS tiles complete

        i32x4 af[4], bf[4];
#pragma unroll
        for (int i = 0; i < 4; ++i) {
            af[i] = *(const i32x4*)(As + (wm + i * 16 + r16) * BK + kq);
            bf[i] = *(const i32x4*)(Bs + (wn + i * 16 + r16) * BK + kq);
        }
#pragma unroll
        for (int im = 0; im < 4; ++im)
#pragma unroll
            for (int in = 0; in < 4; ++in)
                acc[im][in] = __builtin_amdgcn_mfma_i32_16x16x64_i8(
                    af[im], bf[in], acc[im][in], 0, 0, 0);
        __syncthreads();
    }

    // Epilogue. C/D layout (shape-determined): col = lane&15, row = (lane>>4)*4 + reg.
    const float g  = *gamma_p;
    const int cq = (lane >> 4) * 4;
    float bg[4];
#pragma unroll
    for (int in = 0; in < 4; ++in)
        bg[in] = bias[colBase + wn + in * 16 + (lane & 15)] * g;
#pragma unroll
    for (int im = 0; im < 4; ++im) {
        const int rowb = rowBase + wm + im * 16 + cq;
        float sg4[4];
#pragma unroll
        for (int r = 0; r < 4; ++r) sg4[r] = g_sx[rowb + r] * g;
#pragma unroll
        for (int in = 0; in < 4; ++in) {
            const int col = colBase + wn + in * 16 + (lane & 15);
#pragma unroll
            for (int r = 0; r < 4; ++r)
                C[(size_t)(rowb + r) * N + col] = (float)acc[im][in][r] * sg4[r] + bg[in];
        }
    }
}

// ---------------------------------------------------------------------------
// Launch: 4 kernels. No d_ws usage.
// ---------------------------------------------------------------------------
extern "C" void kernel_launch(void* const* d_in, const int* in_sizes, int n_in,
                              void* d_out, int out_size, void* d_ws, size_t ws_size,
                              hipStream_t stream) {
    const float* x     = (const float*)d_in[0];
    const float* w     = (const float*)d_in[1];
    const float* bias  = (const float*)d_in[2];
    const float* gamma = (const float*)d_in[3];
    float* out = (float*)d_out;
    (void)d_ws; (void)ws_size;

    tl_wstats<<<NPART, 256, 0, stream>>>(w);
    tl_wquant<<<NPART, 256, 0, stream>>>(w);
    tl_xquant<<<NROWS, 256, 0, stream>>>(x);

    dim3 grid(OUT_F / 128, NROWS / 128);
    tl_gemm_i8<<<grid, 256, 0, stream>>>(bias, gamma, out);
}

// Round 3
// 425.825 us; speedup vs baseline: 1.1618x; 1.1618x over previous
//
#include <hip/hip_runtime.h>

// Problem constants
#define NROWS 8192   // rows of x / out
#define IN_F  4096   // K
#define OUT_F 4096   // output features
#define NPART 2048   // partial slots (= stats grid size)

typedef __attribute__((ext_vector_type(4))) int i32x4;

// ---------------------------------------------------------------------------
// Static device scratch. Fully rewritten on every kernel_launch call.
// ---------------------------------------------------------------------------
__device__ double g_wsum_p[NPART];                  // per-block sum|w| (fp64)
__device__ float  g_sx[NROWS];                      // per-row x scale = rowmax/127
__device__ signed char g_wq[(size_t)OUT_F * IN_F];  // 16 MiB ternary i8
__device__ signed char g_xq[(size_t)NROWS * IN_F];  // 32 MiB x in i8

// ---------------------------------------------------------------------------
// Kernel 1: w stats pass — sum|w| (fp64), per-block partials. No atomics.
// ---------------------------------------------------------------------------
__global__ __launch_bounds__(256) void tl_wstats(const float* __restrict__ w) {
    const int idx = blockIdx.x * blockDim.x + threadIdx.x;
    const int stride = gridDim.x * blockDim.x;

    double lsum = 0.0;
    const float4* w4 = (const float4*)w;
    for (int i = idx; i < OUT_F * IN_F / 4; i += stride) {
        float4 v = w4[i];
        lsum += (double)fabsf(v.x) + (double)fabsf(v.y) +
                (double)fabsf(v.z) + (double)fabsf(v.w);
    }
    for (int off = 32; off > 0; off >>= 1) lsum += __shfl_down(lsum, off, 64);
    __shared__ double ssum[4];
    int lane = threadIdx.x & 63, wv = threadIdx.x >> 6;
    if (lane == 0) ssum[wv] = lsum;
    __syncthreads();
    if (threadIdx.x == 0)
        g_wsum_p[blockIdx.x] = ssum[0] + ssum[1] + ssum[2] + ssum[3];
}

// ---------------------------------------------------------------------------
// Kernel 2: finalize w stats (per-block recompute from L2-resident partials),
// then quantize w -> ternary i8 (16 elements / thread / iter, 16 B stores).
// ---------------------------------------------------------------------------
__global__ __launch_bounds__(256) void tl_wquant(const float* __restrict__ w) {
    double s = 0.0;
    for (int i = threadIdx.x; i < NPART; i += 256) s += g_wsum_p[i];
    for (int off = 32; off > 0; off >>= 1) s += __shfl_down(s, off, 64);
    __shared__ double ssum[4];
    __shared__ float sh_thresh;
    int lane = threadIdx.x & 63, wv = threadIdx.x >> 6;
    if (lane == 0) ssum[wv] = s;
    __syncthreads();
    if (threadIdx.x == 0) {
        double tot = ssum[0] + ssum[1] + ssum[2] + ssum[3];
        sh_thresh = (float)(0.5 * tot / (double)((size_t)OUT_F * IN_F));
    }
    __syncthreads();
    const float thresh = sh_thresh;

    const int idx = blockIdx.x * blockDim.x + threadIdx.x;
    const int stride = gridDim.x * blockDim.x;

    const float4* w4 = (const float4*)w;
    i32x4* wout = (i32x4*)g_wq;
    for (int i = idx; i < OUT_F * IN_F / 16; i += stride) {
        signed char q[16];
#pragma unroll
        for (int j = 0; j < 4; ++j) {
            float4 v = w4[i * 4 + j];
            q[4*j+0] = v.x > thresh ? 1 : (v.x < -thresh ? -1 : 0);
            q[4*j+1] = v.y > thresh ? 1 : (v.y < -thresh ? -1 : 0);
            q[4*j+2] = v.z > thresh ? 1 : (v.z < -thresh ? -1 : 0);
            q[4*j+3] = v.w > thresh ? 1 : (v.w < -thresh ? -1 : 0);
        }
        i32x4 val; __builtin_memcpy(&val, q, 16);
        wout[i] = val;
    }
}

// ---------------------------------------------------------------------------
// Kernel 3: x per-row quantization, SINGLE PASS (row held in registers).
// scale_m = rowmax/127 factors out of the integer dot product exactly.
// ---------------------------------------------------------------------------
__global__ __launch_bounds__(256) void tl_xquant(const float* __restrict__ x) {
    const int row = blockIdx.x;
    const int tid = threadIdx.x;
    const float4* x4 = (const float4*)(x + (size_t)row * IN_F);

    float4 v[4];
    float lmax = 0.f;
#pragma unroll
    for (int j = 0; j < 4; ++j) {
        v[j] = x4[tid + j * 256];
        lmax = fmaxf(lmax, fmaxf(fmaxf(fabsf(v[j].x), fabsf(v[j].y)),
                                 fmaxf(fabsf(v[j].z), fabsf(v[j].w))));
    }
    for (int off = 32; off > 0; off >>= 1)
        lmax = fmaxf(lmax, __shfl_down(lmax, off, 64));
    __shared__ float smax[4];
    __shared__ float sh_inv;
    int lane = tid & 63, wv = tid >> 6;
    if (lane == 0) smax[wv] = lmax;
    __syncthreads();
    if (tid == 0) {
        float m = fmaxf(fmaxf(smax[0], smax[1]), fmaxf(smax[2], smax[3]));
        g_sx[row] = m * (1.f / 127.f);
        sh_inv = m > 0.f ? 127.f / m : 0.f;
    }
    __syncthreads();
    const float inv = sh_inv;

    int* xout = (int*)(g_xq + (size_t)row * IN_F);
#pragma unroll
    for (int j = 0; j < 4; ++j) {
        signed char q[4];
        q[0] = (signed char)(int)rintf(fminf(fmaxf(v[j].x * inv, -127.f), 127.f));
        q[1] = (signed char)(int)rintf(fminf(fmaxf(v[j].y * inv, -127.f), 127.f));
        q[2] = (signed char)(int)rintf(fminf(fmaxf(v[j].z * inv, -127.f), 127.f));
        q[3] = (signed char)(int)rintf(fminf(fmaxf(v[j].w * inv, -127.f), 127.f));
        int val; __builtin_memcpy(&val, q, 4);
        xout[tid + j * 256] = val;
    }
}

// ---------------------------------------------------------------------------
// Kernel 4: i8 GEMM, 256x256 tile, BK=128 bytes, 8 waves (2M x 4N), double-
// buffered 128 KiB LDS, counted vmcnt(8) pipeline, XOR bank-swizzle
// (row&7)<<4 applied as inverse-permuted global source + swizzled ds_read
// address, setprio around MFMA clusters.
//
// RACE FIX (round 3): barriers are `asm volatile("s_barrier":::"memory")`,
// NOT __builtin_amdgcn_s_barrier(). The builtin is IntrNoMem at LLVM level,
// so the compiler may hoist C-level ds_reads above it — reading LDS chunks
// before OTHER waves' global_load_lds landed (own-wave vmcnt(8) does not
// cover them). The memory clobber pins LDS reads below the barrier and
// staging writes above/below their barriers, with no vmcnt(0) drain.
// ---------------------------------------------------------------------------
#define GLD_LDS(gp, lp) \
    __builtin_amdgcn_global_load_lds( \
        (const __attribute__((address_space(1))) void*)(gp), \
        (__attribute__((address_space(3))) void*)(lp), 16, 0, 0)

__global__ __launch_bounds__(512, 2) void tl_gemm_i8(
    const float* __restrict__ bias,
    const float* __restrict__ gamma_p,
    float* __restrict__ C) {
    constexpr int K = IN_F, N = OUT_F;
    constexpr int BKB = 128;            // K-bytes per tile
    constexpr int KT  = K / BKB;        // 32 K-tiles

    // LDS: buffer b at b*65536; A tile (256 rows x 128 B) at +0, B at +32768.
    // Linear chunk layout (chunk c of 16 B at byte c*16) to match
    // global_load_lds wave-uniform-base + lane*16 scatter.
    __shared__ __align__(16) signed char lds[2 * 65536];   // 128 KiB

    const int tid  = threadIdx.x;
    const int lane = tid & 63;
    const int wave = tid >> 6;
    const int wm   = (wave >> 2) * 128;   // 0 / 128
    const int wn   = (wave & 3) * 64;     // 0 / 64 / 128 / 192
    const int rowBase = blockIdx.y * 256; // M
    const int colBase = blockIdx.x * 256; // N

    // ---- staging source pointers (inverse-swizzled global addresses) ----
    // LDS chunk c: row = c>>3, stored col16 = c&7. It holds the logical
    // element at col16 ^ (row&7)  (XOR swizzle is an involution).
    const signed char* Asrc[4];
    const signed char* Bsrc[4];
#pragma unroll
    for (int j = 0; j < 4; ++j) {
        const int c   = j * 512 + tid;
        const int row = c >> 3;
        const int col = ((c & 7) ^ (row & 7)) * 16;
        Asrc[j] = g_xq + (size_t)(rowBase + row) * K + col;
        Bsrc[j] = g_wq + (size_t)(colBase + row) * K + col;
    }
    char* ldsp = (char*)lds;
    const int stgOff = wave * 1024;       // wave-uniform dest within 8 KiB group

    i32x4 acc[8][4] = {};

    const int r16 = lane & 15;
    const int kq  = (lane >> 4) * 16;
    const int sxz = (lane & 7) << 4;      // read-side swizzle (row&7)<<4, row&7 == lane&7

    // ---- prologue: stage tiles 0 (buf0) and 1 (buf1) ----
#pragma unroll
    for (int b = 0; b < 2; ++b) {
#pragma unroll
        for (int j = 0; j < 4; ++j)
            GLD_LDS(Asrc[j] + b * BKB, ldsp + b * 65536 + j * 8192 + stgOff);
#pragma unroll
        for (int j = 0; j < 4; ++j)
            GLD_LDS(Bsrc[j] + b * BKB, ldsp + b * 65536 + 32768 + j * 8192 + stgOff);
    }

    // One K-tile body. VMC: vmcnt immediate at tile top (8 = next tile's loads
    // may stay in flight; 0 only for the last tile). DO_STAGE: prefetch tile
    // TNEXT into this tile's buffer after all waves finished reading it.
#define TILE_BODY(VMC, BUFB, DO_STAGE, TNEXT)                                 \
    {                                                                         \
        asm volatile("s_waitcnt vmcnt(" #VMC ")" ::: "memory");               \
        asm volatile("s_barrier" ::: "memory");                               \
        const char* pA = ldsp + (BUFB) * 65536 + (wm + r16) * BKB;            \
        const char* pB = ldsp + (BUFB) * 65536 + 32768 + (wn + r16) * BKB;    \
        i32x4 af[8], bf[4];                                                   \
        _Pragma("unroll")                                                     \
        for (int kk = 0; kk < 2; ++kk) {                                      \
            const int cp = (kq + kk * 64) ^ sxz;                              \
            _Pragma("unroll")                                                 \
            for (int im = 0; im < 8; ++im)                                    \
                af[im] = *(const i32x4*)(pA + im * 2048 + cp);                \
            _Pragma("unroll")                                                 \
            for (int in = 0; in < 4; ++in)                                    \
                bf[in] = *(const i32x4*)(pB + in * 2048 + cp);                \
            __builtin_amdgcn_s_setprio(1);                                    \
            _Pragma("unroll")                                                 \
            for (int im = 0; im < 8; ++im)                                    \
                _Pragma("unroll")                                             \
                for (int in = 0; in < 4; ++in)                                \
                    acc[im][in] = __builtin_amdgcn_mfma_i32_16x16x64_i8(      \
                        af[im], bf[in], acc[im][in], 0, 0, 0);                \
            __builtin_amdgcn_s_setprio(0);                                    \
        }                                                                     \
        asm volatile("s_waitcnt lgkmcnt(0)" ::: "memory");                    \
        __builtin_amdgcn_sched_barrier(0);                                    \
        asm volatile("s_barrier" ::: "memory");                               \
        if (DO_STAGE) {                                                       \
            _Pragma("unroll")                                                 \
            for (int j = 0; j < 4; ++j)                                       \
                GLD_LDS(Asrc[j] + (TNEXT) * BKB,                              \
                        ldsp + (BUFB) * 65536 + j * 8192 + stgOff);           \
            _Pragma("unroll")                                                 \
            for (int j = 0; j < 4; ++j)                                       \
                GLD_LDS(Bsrc[j] + (TNEXT) * BKB,                              \
                        ldsp + (BUFB) * 65536 + 32768 + j * 8192 + stgOff);   \
        }                                                                     \
    }

    // Main loop: tiles 0..29 (paired to keep buffer parity compile-time),
    // staging tiles 2..31. Then peel tiles 30 (vmcnt 8) and 31 (vmcnt 0).
    for (int t = 0; t < KT - 2; t += 2) {
        TILE_BODY(8, 0, true, t + 2)
        TILE_BODY(8, 1, true, t + 3)
    }
    TILE_BODY(8, 0, false, 0)
    TILE_BODY(0, 1, false, 0)
#undef TILE_BODY

    // Epilogue. C/D layout: col = lane&15, row = (lane>>4)*4 + reg.
    const float g  = *gamma_p;
    const int cq = (lane >> 4) * 4;
    int   bcol[4];
    float bg[4];
#pragma unroll
    for (int in = 0; in < 4; ++in) {
        bcol[in] = colBase + wn + in * 16 + r16;
        bg[in]   = bias[bcol[in]] * g;
    }
#pragma unroll
    for (int im = 0; im < 8; ++im) {
        const int rowb = rowBase + wm + im * 16 + cq;
        float sg[4];
#pragma unroll
        for (int r = 0; r < 4; ++r) sg[r] = g_sx[rowb + r] * g;
#pragma unroll
        for (int in = 0; in < 4; ++in)
#pragma unroll
            for (int r = 0; r < 4; ++r)
                C[(size_t)(rowb + r) * N + bcol[in]] =
                    (float)acc[im][in][r] * sg[r] + bg[in];
    }
}

// ---------------------------------------------------------------------------
// Launch: 4 kernels. No d_ws usage.
// ---------------------------------------------------------------------------
extern "C" void kernel_launch(void* const* d_in, const int* in_sizes, int n_in,
                              void* d_out, int out_size, void* d_ws, size_t ws_size,
                              hipStream_t stream) {
    const float* x     = (const float*)d_in[0];
    const float* w     = (const float*)d_in[1];
    const float* bias  = (const float*)d_in[2];
    const float* gamma = (const float*)d_in[3];
    float* out = (float*)d_out;
    (void)d_ws; (void)ws_size;

    tl_wstats<<<NPART, 256, 0, stream>>>(w);
    tl_wquant<<<NPART, 256, 0, stream>>>(w);
    tl_xquant<<<NROWS, 256, 0, stream>>>(x);

    dim3 grid(OUT_F / 256, NROWS / 256);
    tl_gemm_i8<<<grid, 512, 0, stream>>>(bias, gamma, out);
}